// Round 9
// baseline (91.726 us; speedup 1.0000x reference)
//
#include <hip/hip_runtime.h>
#include <hip/hip_fp16.h>
#include <hip/hip_cooperative_groups.h>

namespace cg = cooperative_groups;

#define CC 256
#define HH 200
#define WW 304
#define PHW 49    // 7*7
#define XT 16     // x-tile for transpose
#define NCHUNK 2  // channel chunks
#define CHC 128   // channels per chunk
#define SSTR 132  // stage stride (fallback kernel)
#define SSTR2 133 // stage stride (fused kernel; odd -> all 32 banks)
#define GBLK 1024 // cooperative grid size (4 blocks/CU x 256 CU)

struct Interp { int lo, hi; float w0, w1; };

__device__ __forceinline__ Interp axis_interp(float coord, int size) {
  float valid = (coord >= -1.0f && coord <= (float)size) ? 1.0f : 0.0f;
  float c = fminf(fmaxf(coord, 0.0f), (float)(size - 1));
  float fl = floorf(c);
  int lo = (int)fl;
  int hi = min(lo + 1, size - 1);
  float fr = c - fl;
  Interp r;
  r.lo = lo; r.hi = hi;
  r.w0 = (1.0f - fr) * valid;
  r.w1 = fr * valid;
  return r;
}

__device__ __forceinline__ float4 h4_to_f4(ushort4 u) {
  __half2 a = *(__half2*)&u.x;
  __half2 b = *(__half2*)&u.z;
  float2 fa = __half22float2(a);
  float2 fb = __half22float2(b);
  return make_float4(fa.x, fa.y, fb.x, fb.y);
}

// Deterministic stable bucket sort via per-wave ballot ranking. ~2-3 us.
__global__ __launch_bounds__(1024) void k_sortrois(const float* __restrict__ rois,
                                                   int K, int Bp,
                                                   int* __restrict__ perm) {
  __shared__ int whist[16][32];
  __shared__ int keytot[32];
  __shared__ int keybase[32];
  int tid = threadIdx.x;
  if (K > 1024) {
    for (int i = tid; i < K; i += 1024) perm[i] = i;
    return;
  }
  int wave = tid >> 6, lane = tid & 63;
  bool active = tid < K;
  int key = 63;
  if (active) {
    const float* r = rois + (size_t)tid * 5;
    int b = (int)r[0];
    float cx = (r[1] + r[3]) * 0.125f;
    float cy = (r[2] + r[4]) * 0.125f;
    int rx = (int)(cx * (8.0f / (float)WW)); rx = max(0, min(7, rx));
    int ry = cy >= (float)(HH / 2) ? 1 : 0;
    key = (((b & 1) * 2 + ry) * 8 + rx) & 31;
  }
  if (tid < 512) ((int*)whist)[tid] = 0;
  __syncthreads();
  unsigned long long m = ~0ull;
#pragma unroll
  for (int bit = 0; bit < 6; ++bit) {
    unsigned long long bb = __ballot((key >> bit) & 1);
    m &= ((key >> bit) & 1) ? bb : ~bb;
  }
  unsigned long long below = m & ((1ull << lane) - 1ull);
  int rank = __popcll(below);
  if (active && below == 0ull) whist[wave][key] = __popcll(m);
  __syncthreads();
  if (tid < 32) {
    int total = 0;
    for (int w = 0; w < 16; ++w) {
      int t = whist[w][tid];
      whist[w][tid] = total;
      total += t;
    }
    keytot[tid] = total;
  }
  __syncthreads();
  if (tid == 0) {
    int base = 0;
    for (int k2 = 0; k2 < 32; ++k2) { keybase[k2] = base; base += keytot[k2]; }
  }
  __syncthreads();
  if (active) perm[keybase[key] + whist[wave][key] + rank] = tid;
}

// ===================== Fused cooperative kernel =====================
// Phase 1: NCHW fp32 -> chunked NHWC fp16 (grid-stride over 16x tiles).
// grid.sync()
// Phase 2: gather; block handles pairs (chunk-major), XCD-swizzled slots.
__global__ __launch_bounds__(512, 8) void k_fused(const float* __restrict__ src,
                                                  __half* __restrict__ feat,
                                                  const float* __restrict__ rois,
                                                  const int* __restrict__ perm,
                                                  float* __restrict__ out,
                                                  int K, int Bp) {
  __shared__ float shbuf[PHW * SSTR2];   // 26.07 KB; also holds 16x260 tile
  __shared__ int   xoff[14][2];
  __shared__ float xwgt[14][2];
  __shared__ int2  yoff[14];
  __shared__ float2 ywgt[14];

  int tid = threadIdx.x;
  int bid = blockIdx.x;

  // ---- Phase 1: transpose ----
  {
    float (*tile)[CC + 4] = (float (*)[CC + 4])shbuf;
    int ntx = WW / XT;                   // 19
    int nTiles = ntx * (Bp * HH);
    int cr = tid >> 2;                   // 0..127
    int x4 = (tid & 3) * 4;
    int xw = tid >> 5;                   // 0..15
    int co = (tid & 31) * 8;
    int chunk = co >> 7;
    int cc = co & 127;
    for (int t = bid; t < nTiles; t += GBLK) {
      int xt = t % ntx;
      int plane = t / ntx;
      int b = plane / HH;
      int y = plane - b * HH;
      int x0 = xt * XT;
      const float* sp = src + (size_t)b * CC * HH * WW + (size_t)y * WW + x0;
      __syncthreads();                   // tile reuse guard
#pragma unroll
      for (int pass = 0; pass < 2; ++pass) {
        int c = cr + pass * 128;
        float4 v = *(const float4*)(sp + (size_t)c * HH * WW + x4);
        tile[x4 + 0][c] = v.x;
        tile[x4 + 1][c] = v.y;
        tile[x4 + 2][c] = v.z;
        tile[x4 + 3][c] = v.w;
      }
      __syncthreads();
      const float* trow = &tile[xw][co];
      union { int4 i4; __half2 h[4]; } pk;
      pk.h[0] = __floats2half2_rn(trow[0], trow[1]);
      pk.h[1] = __floats2half2_rn(trow[2], trow[3]);
      pk.h[2] = __floats2half2_rn(trow[4], trow[5]);
      pk.h[3] = __floats2half2_rn(trow[6], trow[7]);
      size_t idx = (((size_t)chunk * Bp + b) * (size_t)(HH * WW) +
                    (size_t)y * WW + (x0 + xw)) * CHC + cc;
      *(int4*)(feat + idx) = pk.i4;
    }
  }
  cg::this_grid().sync();

  // ---- Phase 2: gather ----
  {
    float (*stage)[SSTR2] = (float (*)[SSTR2])shbuf;
    int q = (K + 7) / 8;
    int pairsPerChunk = 8 * q;
    int nPairs = NCHUNK * pairsPerChunk;
    int lane = tid & 63;
    int wave = tid >> 6;
    int xsel = (lane >> 4) & 1;
    int ysel = lane >> 5;
    int cq = lane & 15;                  // 8 channels each
    int cqByte = cq * 16;

    for (int pair = bid; pair < nPairs; pair += GBLK) {
      int chunk = pair / pairsPerChunk;
      int si = pair - chunk * pairsPerChunk;
      int slot = (si & 7) * q + (si >> 3);
      __syncthreads();                   // stage+tables reuse guard
      if (slot >= K) continue;
      int k = perm[slot];
      const float* r = rois + (size_t)k * 5;
      int b = __builtin_amdgcn_readfirstlane((int)r[0]);
      float x1 = r[1] * 0.25f, y1 = r[2] * 0.25f;
      float x2 = r[3] * 0.25f, y2 = r[4] * 0.25f;
      float bin_w = fmaxf(x2 - x1, 1.0f) * (1.0f / 7.0f);
      float bin_h = fmaxf(y2 - y1, 1.0f) * (1.0f / 7.0f);
      if (tid < 32) {
        int axis = tid >> 4;
        int j = tid & 15;
        if (j < 14) {
          float start = axis ? y1 : x1;
          float binsz = axis ? bin_h : bin_w;
          int size = axis ? HH : WW;
          float coord = start + ((float)j + 0.5f) * 0.5f * binsz;
          Interp ii = axis_interp(coord, size);
          if (axis) {
            yoff[j] = make_int2(ii.lo * (WW * CHC * 2), ii.hi * (WW * CHC * 2));
            ywgt[j] = make_float2(ii.w0, ii.w1);
          } else {
            xoff[j][0] = ii.lo * (CHC * 2);
            xoff[j][1] = ii.hi * (CHC * 2);
            xwgt[j][0] = ii.w0 * 0.25f;
            xwgt[j][1] = ii.w1 * 0.25f;
          }
        }
      }
      __syncthreads();

      const char* fb = (const char*)feat +
          ((size_t)chunk * Bp + b) * (size_t)(HH * WW) * (CHC * 2);

      for (int p = wave; p < PHW; p += 8) {
        int ph = p / 7;
        int pw = p - ph * 7;
        int jx0 = 2 * pw, jy0 = 2 * ph;
        float acc[8] = {0.f, 0.f, 0.f, 0.f, 0.f, 0.f, 0.f, 0.f};
#pragma unroll
        for (int s = 0; s < 4; ++s) {    // s = (sy<<1)|sx
          int jx = jx0 + (s & 1);
          int jy = jy0 + (s >> 1);
          int xo = xoff[jx][xsel];
          int2 yy = yoff[jy];
          int yo = ysel ? yy.y : yy.x;
          float2 yw = ywgt[jy];
          float w = xwgt[jx][xsel] * (ysel ? yw.y : yw.x);
          union { int4 i4; __half2 h[4]; } u;
          u.i4 = *(const int4*)(fb + ((size_t)(yo + xo) + cqByte));
          __half2 wh = __float2half2_rn(w);
#pragma unroll
          for (int i = 0; i < 4; ++i) {
            float2 f = __half22float2(__hmul2(u.h[i], wh));
            acc[2 * i] += f.x;
            acc[2 * i + 1] += f.y;
          }
        }
        // reduce over xsel (xor 16) then ysel (xor 32)
#pragma unroll
        for (int i = 0; i < 8; ++i) acc[i] += __shfl_xor(acc[i], 16);
#pragma unroll
        for (int i = 0; i < 8; ++i) acc[i] += __shfl_xor(acc[i], 32);
        if (lane < 16) {
          float* sdst = &stage[p][cq * 8];
#pragma unroll
          for (int i = 0; i < 8; ++i) sdst[i] = acc[i];
        }
      }
      __syncthreads();

      float* outk = out + (size_t)k * CC * PHW + (size_t)chunk * CHC * PHW;
      for (int i = tid; i < CHC * PHW; i += 512) {
        int cc2 = i / PHW;
        int p = i - cc2 * PHW;
        outk[i] = stage[p][cc2];
      }
    }
  }
}

// ===================== Fallback pipeline (R7, known-good) =====================
__global__ __launch_bounds__(256) void k_transpose_f16c(const float* __restrict__ src,
                                                        __half* __restrict__ dst,
                                                        int Bp) {
  __shared__ float tile[XT][CC + 4];
  int plane = blockIdx.y;
  int x0 = blockIdx.x * XT;
  int b = plane / HH;
  int y = plane - b * HH;
  const float* sp = src + (size_t)b * CC * HH * WW + (size_t)y * WW + x0;
  int cr = threadIdx.x >> 2;
  int x4 = (threadIdx.x & 3) * 4;
#pragma unroll
  for (int pass = 0; pass < 4; ++pass) {
    int c = cr + pass * 64;
    float4 v = *(const float4*)(sp + (size_t)c * HH * WW + x4);
    tile[x4 + 0][c] = v.x;
    tile[x4 + 1][c] = v.y;
    tile[x4 + 2][c] = v.z;
    tile[x4 + 3][c] = v.w;
  }
  __syncthreads();
  int xw = threadIdx.x >> 5;
  int co = (threadIdx.x & 31) * 8;
  int chunk = co >> 7;
  int cc = co & 127;
#pragma unroll
  for (int pass = 0; pass < 2; ++pass) {
    int x = xw + pass * 8;
    const float* trow = &tile[x][co];
    union { uint4 u; __half2 h[4]; } pk;
    pk.h[0] = __floats2half2_rn(trow[0], trow[1]);
    pk.h[1] = __floats2half2_rn(trow[2], trow[3]);
    pk.h[2] = __floats2half2_rn(trow[4], trow[5]);
    pk.h[3] = __floats2half2_rn(trow[6], trow[7]);
    size_t idx = (((size_t)chunk * Bp + b) * (size_t)(HH * WW) +
                  (size_t)y * WW + (x0 + x)) * CHC + cc;
    *(uint4*)(dst + idx) = pk.u;
  }
}

__global__ __launch_bounds__(512, 8) void k_gather(const __half* __restrict__ feat,
                                                   const float* __restrict__ rois,
                                                   const int* __restrict__ perm,
                                                   float* __restrict__ out,
                                                   int K, int Bp) {
  __shared__ float stage[PHW][SSTR];
  __shared__ int   xoff[14][2];
  __shared__ float xwgt[14][2];
  __shared__ int2  yoff[14];
  __shared__ float2 ywgt[14];
  int q = gridDim.x >> 3;
  int bx = blockIdx.x;
  int slot = (bx & 7) * q + (bx >> 3);
  if (slot >= K) return;
  int k = perm[slot];
  int chunk = blockIdx.y;

  const float* r = rois + (size_t)k * 5;
  int b = __builtin_amdgcn_readfirstlane((int)r[0]);
  float x1 = r[1] * 0.25f, y1 = r[2] * 0.25f;
  float x2 = r[3] * 0.25f, y2 = r[4] * 0.25f;
  float bin_w = fmaxf(x2 - x1, 1.0f) * (1.0f / 7.0f);
  float bin_h = fmaxf(y2 - y1, 1.0f) * (1.0f / 7.0f);

  int tid = threadIdx.x;
  if (tid < 32) {
    int axis = tid >> 4;
    int j = tid & 15;
    if (j < 14) {
      float start = axis ? y1 : x1;
      float binsz = axis ? bin_h : bin_w;
      int size = axis ? HH : WW;
      float coord = start + ((float)j + 0.5f) * 0.5f * binsz;
      Interp ii = axis_interp(coord, size);
      if (axis) {
        yoff[j] = make_int2(ii.lo * (WW * CHC * 2), ii.hi * (WW * CHC * 2));
        ywgt[j] = make_float2(ii.w0, ii.w1);
      } else {
        xoff[j][0] = ii.lo * (CHC * 2);
        xoff[j][1] = ii.hi * (CHC * 2);
        xwgt[j][0] = ii.w0 * 0.25f;
        xwgt[j][1] = ii.w1 * 0.25f;
      }
    }
  }
  __syncthreads();

  int wave = tid >> 6;
  int lane = tid & 63;
  int xsel = lane >> 5;
  int cq = lane & 31;
  const char* fb = (const char*)(feat +
      ((size_t)chunk * Bp + b) * (size_t)(HH * WW) * CHC);
  int laneByte = cq * 8;

  for (int p = wave; p < PHW; p += 8) {
    int ph = p / 7;
    int pw = p - ph * 7;
    int jx0 = 2 * pw, jy0 = 2 * ph;
    int2 yo0 = yoff[jy0], yo1 = yoff[jy0 + 1];
    float2 yw0 = ywgt[jy0], yw1 = ywgt[jy0 + 1];
    __half2 w00 = __float2half2_rn(yw0.x), w01 = __float2half2_rn(yw0.y);
    __half2 w10 = __float2half2_rn(yw1.x), w11 = __float2half2_rn(yw1.y);
    float ax = 0.f, ay = 0.f, az = 0.f, aw = 0.f;
#pragma unroll
    for (int sx = 0; sx < 2; ++sx) {
      int xo = xoff[jx0 + sx][xsel] + laneByte;
      float wx = xwgt[jx0 + sx][xsel];
#pragma unroll
      for (int sy = 0; sy < 2; ++sy) {
        const __half2 wlo = sy ? w10 : w00;
        const __half2 whi = sy ? w11 : w01;
        int2 yo = sy ? yo1 : yo0;
        ushort4 u0 = *(const ushort4*)(fb + (yo.x + xo));
        ushort4 u1 = *(const ushort4*)(fb + (yo.y + xo));
        __half2 t0 = __hfma2(*(__half2*)&u1.x, whi, __hmul2(*(__half2*)&u0.x, wlo));
        __half2 t1 = __hfma2(*(__half2*)&u1.z, whi, __hmul2(*(__half2*)&u0.z, wlo));
        float2 f0 = __half22float2(t0);
        float2 f1 = __half22float2(t1);
        ax += wx * f0.x; ay += wx * f0.y;
        az += wx * f1.x; aw += wx * f1.y;
      }
    }
    ax += __shfl_xor(ax, 32);
    ay += __shfl_xor(ay, 32);
    az += __shfl_xor(az, 32);
    aw += __shfl_xor(aw, 32);
    if (lane < 32) {
      float* s = &stage[p][cq * 4];
      s[0] = ax; s[1] = ay; s[2] = az; s[3] = aw;
    }
  }
  __syncthreads();

  float* outk = out + (size_t)k * CC * PHW + (size_t)chunk * CHC * PHW;
  for (int i = tid; i < CHC * PHW; i += 512) {
    int cc = i / PHW;
    int p = i - cc * PHW;
    outk[i] = stage[p][cc];
  }
}

__global__ __launch_bounds__(256) void k_roialign_direct(const float* __restrict__ fe,
                                                         const float* __restrict__ rois,
                                                         float* __restrict__ out,
                                                         int total) {
  int idx = blockIdx.x * 256 + threadIdx.x;
  if (idx >= total) return;
  int pw = idx % 7;
  int t = idx / 7;
  int ph = t % 7; t /= 7;
  int c = t % CC;
  int k = t / CC;
  const float* r = rois + (size_t)k * 5;
  int b = (int)r[0];
  float x1 = r[1] * 0.25f, y1 = r[2] * 0.25f;
  float x2 = r[3] * 0.25f, y2 = r[4] * 0.25f;
  float bin_w = fmaxf(x2 - x1, 1.0f) * (1.0f / 7.0f);
  float bin_h = fmaxf(y2 - y1, 1.0f) * (1.0f / 7.0f);
  const float* base = fe + ((size_t)b * CC + c) * HH * WW;
  float acc = 0.f;
#pragma unroll
  for (int sy = 0; sy < 2; ++sy) {
    float yy = y1 + ((float)(2 * ph + sy) + 0.5f) * 0.5f * bin_h;
    Interp iy = axis_interp(yy, HH);
#pragma unroll
    for (int sx = 0; sx < 2; ++sx) {
      float xx = x1 + ((float)(2 * pw + sx) + 0.5f) * 0.5f * bin_w;
      Interp ix = axis_interp(xx, WW);
      float v00 = base[(size_t)iy.lo * WW + ix.lo];
      float v01 = base[(size_t)iy.lo * WW + ix.hi];
      float v10 = base[(size_t)iy.hi * WW + ix.lo];
      float v11 = base[(size_t)iy.hi * WW + ix.hi];
      acc += iy.w0 * ix.w0 * v00 + iy.w0 * ix.w1 * v01 +
             iy.w1 * ix.w0 * v10 + iy.w1 * ix.w1 * v11;
    }
  }
  out[idx] = acc * 0.25f;
}

extern "C" void kernel_launch(void* const* d_in, const int* in_sizes, int n_in,
                              void* d_out, int out_size, void* d_ws, size_t ws_size,
                              hipStream_t stream) {
  const float* features = (const float*)d_in[0];
  const float* rois = (const float*)d_in[1];
  float* out = (float*)d_out;
  int B = in_sizes[0] / (CC * HH * WW);
  int K = in_sizes[1] / 5;
  size_t feat_bytes = (size_t)B * HH * WW * CC * sizeof(__half);
  size_t perm_bytes = (size_t)((K + 7) & ~7) * sizeof(int);

  if (ws_size >= feat_bytes + perm_bytes && K <= 1024) {
    __half* feat16 = (__half*)d_ws;
    int* perm = (int*)((char*)d_ws + feat_bytes);

    // Capture-safe host queries (no stream ops, deterministic).
    int maxPerCU = 0, coopAttr = 0, numCU = 0;
    hipError_t e1 = hipOccupancyMaxActiveBlocksPerMultiprocessor(
        &maxPerCU, k_fused, 512, 0);
    (void)hipDeviceGetAttribute(&coopAttr, hipDeviceAttributeCooperativeLaunch, 0);
    (void)hipDeviceGetAttribute(&numCU, hipDeviceAttributeMultiprocessorCount, 0);
    bool coop_ok = (e1 == hipSuccess) && coopAttr && (maxPerCU * numCU >= GBLK);

    k_sortrois<<<1, 1024, 0, stream>>>(rois, K, B, perm);
    if (coop_ok) {
      void* args[] = {(void*)&features, (void*)&feat16, (void*)&rois,
                      (void*)&perm, (void*)&out, (void*)&K, (void*)&B};
      (void)hipLaunchCooperativeKernel((void*)k_fused, dim3(GBLK), dim3(512),
                                       args, 0, stream);
    } else {
      dim3 tg(WW / XT, B * HH);
      k_transpose_f16c<<<tg, 256, 0, stream>>>(features, feat16, B);
      int q = (K + 7) / 8;
      dim3 gg(8 * q, NCHUNK);
      k_gather<<<gg, 512, 0, stream>>>(feat16, rois, perm, out, K, B);
    }
  } else {
    int total = K * CC * PHW;
    k_roialign_direct<<<(total + 255) / 256, 256, 0, stream>>>(features, rois, out, total);
  }
}

// Round 10
// 91.255 us; speedup vs baseline: 1.0052x; 1.0052x over previous
//
#include <hip/hip_runtime.h>
#include <hip/hip_fp16.h>

#define CC 256
#define HH 200
#define WW 304
#define PHW 49    // 7*7
#define XT 16     // x-tile for transpose
#define NCHUNK 4  // channel chunks
#define CHC 64    // channels per chunk -> per-(XCD,bucket) set ~2.6MB, fits 4MB L2
#define SSTR 65   // stage row stride (floats, odd -> spread banks)

struct Interp { int lo, hi; float w0, w1; };

__device__ __forceinline__ Interp axis_interp(float coord, int size) {
  float valid = (coord >= -1.0f && coord <= (float)size) ? 1.0f : 0.0f;
  float c = fminf(fmaxf(coord, 0.0f), (float)(size - 1));
  float fl = floorf(c);
  int lo = (int)fl;
  int hi = min(lo + 1, size - 1);
  float fr = c - fl;
  Interp r;
  r.lo = lo; r.hi = hi;
  r.w0 = (1.0f - fr) * valid;
  r.w1 = fr * valid;
  return r;
}

// Deterministic stable bucket sort via per-wave ballot ranking. ~2-3 us.
__global__ __launch_bounds__(1024) void k_sortrois(const float* __restrict__ rois,
                                                   int K, int Bp,
                                                   int* __restrict__ perm) {
  __shared__ int whist[16][32];
  __shared__ int keytot[32];
  __shared__ int keybase[32];
  int tid = threadIdx.x;
  if (K > 1024) {
    for (int i = tid; i < K; i += 1024) perm[i] = i;
    return;
  }
  int wave = tid >> 6, lane = tid & 63;
  bool active = tid < K;
  int key = 63;
  if (active) {
    const float* r = rois + (size_t)tid * 5;
    int b = (int)r[0];
    float cx = (r[1] + r[3]) * 0.125f;
    float cy = (r[2] + r[4]) * 0.125f;
    int rx = (int)(cx * (8.0f / (float)WW)); rx = max(0, min(7, rx));
    int ry = cy >= (float)(HH / 2) ? 1 : 0;
    key = (((b & 1) * 2 + ry) * 8 + rx) & 31;
  }
  if (tid < 512) ((int*)whist)[tid] = 0;
  __syncthreads();
  unsigned long long m = ~0ull;
#pragma unroll
  for (int bit = 0; bit < 6; ++bit) {
    unsigned long long bb = __ballot((key >> bit) & 1);
    m &= ((key >> bit) & 1) ? bb : ~bb;
  }
  unsigned long long below = m & ((1ull << lane) - 1ull);
  int rank = __popcll(below);
  if (active && below == 0ull) whist[wave][key] = __popcll(m);
  __syncthreads();
  if (tid < 32) {
    int total = 0;
    for (int w = 0; w < 16; ++w) {
      int t = whist[w][tid];
      whist[w][tid] = total;
      total += t;
    }
    keytot[tid] = total;
  }
  __syncthreads();
  if (tid == 0) {
    int base = 0;
    for (int k2 = 0; k2 < 32; ++k2) { keybase[k2] = base; base += keytot[k2]; }
  }
  __syncthreads();
  if (active) perm[keybase[key] + whist[wave][key] + rank] = tid;
}

// NCHW fp32 -> chunked NHWC fp16: dst[((chunk*B+b)*H*W + y*W + x)*CHC + c%CHC]
__global__ __launch_bounds__(256) void k_transpose_f16c(const float* __restrict__ src,
                                                        __half* __restrict__ dst,
                                                        int Bp) {
  __shared__ float tile[XT][CC + 4];
  int plane = blockIdx.y;              // b*HH + y
  int x0 = blockIdx.x * XT;            // WW == 19*16
  int b = plane / HH;
  int y = plane - b * HH;
  const float* sp = src + (size_t)b * CC * HH * WW + (size_t)y * WW + x0;
  int cr = threadIdx.x >> 2;           // 0..63
  int x4 = (threadIdx.x & 3) * 4;      // 0,4,8,12
#pragma unroll
  for (int pass = 0; pass < 4; ++pass) {
    int c = cr + pass * 64;
    float4 v = *(const float4*)(sp + (size_t)c * HH * WW + x4);
    tile[x4 + 0][c] = v.x;
    tile[x4 + 1][c] = v.y;
    tile[x4 + 2][c] = v.z;
    tile[x4 + 3][c] = v.w;
  }
  __syncthreads();
  int xw = threadIdx.x >> 5;           // 0..7
  int co = (threadIdx.x & 31) * 8;     // global channel 0..248
  int chunk = co >> 6;                 // CHC=64
  int cc = co & 63;
#pragma unroll
  for (int pass = 0; pass < 2; ++pass) {
    int x = xw + pass * 8;
    const float* trow = &tile[x][co];
    union { uint4 u; __half2 h[4]; } pk;
    pk.h[0] = __floats2half2_rn(trow[0], trow[1]);
    pk.h[1] = __floats2half2_rn(trow[2], trow[3]);
    pk.h[2] = __floats2half2_rn(trow[4], trow[5]);
    pk.h[3] = __floats2half2_rn(trow[6], trow[7]);
    size_t idx = (((size_t)chunk * Bp + b) * (size_t)(HH * WW) +
                  (size_t)y * WW + (x0 + x)) * CHC + cc;
    *(uint4*)(dst + idx) = pk.u;
  }
}

// Grid (8*q slots, NCHUNK), XCD-swizzled sorted slots -> per-XCD L2 locality.
// Lane: xsel = lane>>5 (x-corner, half-wave), cq = lane&31 (2 channels, 4B).
// Per-ROI premultiplied byte-offset tables; fp16 y-interp; fp32 x-acc.
__global__ __launch_bounds__(512, 8) void k_gather(const __half* __restrict__ feat,
                                                   const float* __restrict__ rois,
                                                   const int* __restrict__ perm,
                                                   float* __restrict__ out,
                                                   int K, int Bp) {
  __shared__ float stage[PHW][SSTR];
  __shared__ int   xoff[14][2];   // xi * CHC*2 (bytes)
  __shared__ float xwgt[14][2];   // wx * 0.25 folded
  __shared__ int2  yoff[14];      // (ylo, yhi) * WW*CHC*2 (bytes)
  __shared__ float2 ywgt[14];     // (w0, w1)
  int q = gridDim.x >> 3;
  int bx = blockIdx.x;
  int slot = (bx & 7) * q + (bx >> 3);
  if (slot >= K) return;
  int k = perm[slot];
  int chunk = blockIdx.y;

  const float* r = rois + (size_t)k * 5;
  int b = __builtin_amdgcn_readfirstlane((int)r[0]);
  float x1 = r[1] * 0.25f, y1 = r[2] * 0.25f;
  float x2 = r[3] * 0.25f, y2 = r[4] * 0.25f;
  float bin_w = fmaxf(x2 - x1, 1.0f) * (1.0f / 7.0f);
  float bin_h = fmaxf(y2 - y1, 1.0f) * (1.0f / 7.0f);

  int tid = threadIdx.x;
  if (tid < 32) {                 // interp tables: x on tid 0..13, y on 16..29
    int axis = tid >> 4;
    int j = tid & 15;
    if (j < 14) {
      float start = axis ? y1 : x1;
      float binsz = axis ? bin_h : bin_w;
      int size = axis ? HH : WW;
      float coord = start + ((float)j + 0.5f) * 0.5f * binsz;
      Interp ii = axis_interp(coord, size);
      if (axis) {
        yoff[j] = make_int2(ii.lo * (WW * CHC * 2), ii.hi * (WW * CHC * 2));
        ywgt[j] = make_float2(ii.w0, ii.w1);
      } else {
        xoff[j][0] = ii.lo * (CHC * 2);
        xoff[j][1] = ii.hi * (CHC * 2);
        xwgt[j][0] = ii.w0 * 0.25f;
        xwgt[j][1] = ii.w1 * 0.25f;
      }
    }
  }
  __syncthreads();

  int wave = tid >> 6;            // 0..7
  int lane = tid & 63;
  int xsel = lane >> 5;           // x-corner select (half-wave)
  int cq = lane & 31;             // channel pair within chunk
  const char* fb = (const char*)(feat +
      ((size_t)chunk * Bp + b) * (size_t)(HH * WW) * CHC);
  int laneByte = cq * 4;          // ushort2 = 4 B

  for (int p = wave; p < PHW; p += 8) {
    int ph = p / 7;
    int pw = p - ph * 7;
    int jx0 = 2 * pw, jy0 = 2 * ph;
    int2 yo0 = yoff[jy0], yo1 = yoff[jy0 + 1];
    float2 yw0 = ywgt[jy0], yw1 = ywgt[jy0 + 1];
    __half2 w00 = __float2half2_rn(yw0.x), w01 = __float2half2_rn(yw0.y);
    __half2 w10 = __float2half2_rn(yw1.x), w11 = __float2half2_rn(yw1.y);
    float ax = 0.f, ay = 0.f;
#pragma unroll
    for (int sx = 0; sx < 2; ++sx) {
      int xo = xoff[jx0 + sx][xsel] + laneByte;
      float wx = xwgt[jx0 + sx][xsel];
#pragma unroll
      for (int sy = 0; sy < 2; ++sy) {
        const __half2 wlo = sy ? w10 : w00;
        const __half2 whi = sy ? w11 : w01;
        int2 yo = sy ? yo1 : yo0;
        ushort2 u0 = *(const ushort2*)(fb + (yo.x + xo));
        ushort2 u1 = *(const ushort2*)(fb + (yo.y + xo));
        __half2 t = __hfma2(*(__half2*)&u1, whi, __hmul2(*(__half2*)&u0, wlo));
        float2 f = __half22float2(t);
        ax += wx * f.x;
        ay += wx * f.y;
      }
    }
    ax += __shfl_xor(ax, 32);
    ay += __shfl_xor(ay, 32);
    if (lane < 32) {
      stage[p][cq * 2 + 0] = ax;
      stage[p][cq * 2 + 1] = ay;
    }
  }
  __syncthreads();

  // Contiguous coalesced write: out[k][chunk*CHC+cc][p], linear in i.
  float* outk = out + (size_t)k * CC * PHW + (size_t)chunk * CHC * PHW;
  for (int i = tid; i < CHC * PHW; i += 512) {
    int cc = i / PHW;
    int p = i - cc * PHW;
    outk[i] = stage[p][cc];
  }
}

// Fallback if workspace too small: one thread per output element, NCHW fp32.
__global__ __launch_bounds__(256) void k_roialign_direct(const float* __restrict__ fe,
                                                         const float* __restrict__ rois,
                                                         float* __restrict__ out,
                                                         int total) {
  int idx = blockIdx.x * 256 + threadIdx.x;
  if (idx >= total) return;
  int pw = idx % 7;
  int t = idx / 7;
  int ph = t % 7; t /= 7;
  int c = t % CC;
  int k = t / CC;
  const float* r = rois + (size_t)k * 5;
  int b = (int)r[0];
  float x1 = r[1] * 0.25f, y1 = r[2] * 0.25f;
  float x2 = r[3] * 0.25f, y2 = r[4] * 0.25f;
  float bin_w = fmaxf(x2 - x1, 1.0f) * (1.0f / 7.0f);
  float bin_h = fmaxf(y2 - y1, 1.0f) * (1.0f / 7.0f);
  const float* base = fe + ((size_t)b * CC + c) * HH * WW;
  float acc = 0.f;
#pragma unroll
  for (int sy = 0; sy < 2; ++sy) {
    float yy = y1 + ((float)(2 * ph + sy) + 0.5f) * 0.5f * bin_h;
    Interp iy = axis_interp(yy, HH);
#pragma unroll
    for (int sx = 0; sx < 2; ++sx) {
      float xx = x1 + ((float)(2 * pw + sx) + 0.5f) * 0.5f * bin_w;
      Interp ix = axis_interp(xx, WW);
      float v00 = base[(size_t)iy.lo * WW + ix.lo];
      float v01 = base[(size_t)iy.lo * WW + ix.hi];
      float v10 = base[(size_t)iy.hi * WW + ix.lo];
      float v11 = base[(size_t)iy.hi * WW + ix.hi];
      acc += iy.w0 * ix.w0 * v00 + iy.w0 * ix.w1 * v01 +
             iy.w1 * ix.w0 * v10 + iy.w1 * ix.w1 * v11;
    }
  }
  out[idx] = acc * 0.25f;
}

extern "C" void kernel_launch(void* const* d_in, const int* in_sizes, int n_in,
                              void* d_out, int out_size, void* d_ws, size_t ws_size,
                              hipStream_t stream) {
  const float* features = (const float*)d_in[0];
  const float* rois = (const float*)d_in[1];
  float* out = (float*)d_out;
  int B = in_sizes[0] / (CC * HH * WW);
  int K = in_sizes[1] / 5;
  size_t feat_bytes = (size_t)B * HH * WW * CC * sizeof(__half);
  size_t perm_bytes = (size_t)((K + 7) & ~7) * sizeof(int);
  if (ws_size >= feat_bytes + perm_bytes && K <= 1024) {
    __half* feat16 = (__half*)d_ws;
    int* perm = (int*)((char*)d_ws + feat_bytes);
    k_sortrois<<<1, 1024, 0, stream>>>(rois, K, B, perm);
    dim3 tg(WW / XT, B * HH);          // 19 x 400
    k_transpose_f16c<<<tg, 256, 0, stream>>>(features, feat16, B);
    int q = (K + 7) / 8;
    dim3 gg(8 * q, NCHUNK);
    k_gather<<<gg, 512, 0, stream>>>(feat16, rois, perm, out, K, B);
  } else {
    int total = K * CC * PHW;
    k_roialign_direct<<<(total + 255) / 256, 256, 0, stream>>>(features, rois, out, total);
  }
}